// Round 1
// baseline (1667.875 us; speedup 1.0000x reference)
//
#include <hip/hip_runtime.h>
#include <stdint.h>

typedef unsigned long long u64;
typedef unsigned int u32;

#define NB 8
#define NN 2048
#define NC 80
#define ROW 84
#define OUT_K 200
#define IOU_T 0.5f
#define SCORE_T 0.01f

// ---- bitonic helpers on 2048-element u64 arrays in LDS, descending ----
__device__ __forceinline__ void bitonic_sort_desc_2048(u64* a, int tid) {
    for (int k = 2; k <= 2048; k <<= 1) {
        for (int j = k >> 1; j > 0; j >>= 1) {
            for (int i = tid; i < 2048; i += 256) {
                int ixj = i ^ j;
                if (ixj > i) {
                    u64 x = a[i], y = a[ixj];
                    bool up = ((i & k) == 0);
                    // descending sort: invert classic ascending comparator
                    if (up ? (x < y) : (x > y)) { a[i] = y; a[ixj] = x; }
                }
            }
            __syncthreads();
        }
    }
}

__device__ __forceinline__ void bitonic_merge_desc_2048(u64* a, int tid) {
    for (int j = 1024; j > 0; j >>= 1) {
        for (int i = tid; i < 2048; i += 256) {
            int ixj = i ^ j;
            if (ixj > i) {
                u64 x = a[i], y = a[ixj];
                if (x < y) { a[i] = y; a[ixj] = x; }
            }
        }
        __syncthreads();
    }
}

// ---- Kernel A: one block per (batch, class) -> greedy NMS, first 200 kept ----
__global__ __launch_bounds__(256) void nms_class_kernel(
        const float* __restrict__ x, u64* __restrict__ cand_key,
        u32* __restrict__ cand_idx) {
    const int bc = blockIdx.x;
    const int b = bc / NC;
    const int c = bc % NC;
    const int tid = threadIdx.x;

    __shared__ u64 key[NN];          // (score_bits<<32) | (0xFFFFFFFF - orig_idx)
    __shared__ float4 sbox[NN];      // boxes in sorted order
    __shared__ int keep[NN];
    __shared__ int s_slots[OUT_K];   // sorted-position of each kept box
    __shared__ int s_i, s_kept, s_done, s_cur;
    __shared__ float4 s_curbox;

    const float* xb = x + (size_t)b * NN * ROW;

    // load scores for this class, build sort keys (score desc, index asc)
    for (int n = tid; n < NN; n += 256) {
        float sc = xb[n * ROW + 4 + c];                 // scores >= 0 -> bits monotone
        u32 bits = __float_as_uint(sc);
        key[n] = ((u64)bits << 32) | (u64)(0xFFFFFFFFu - (u32)n);
        keep[n] = 1;
    }
    __syncthreads();
    bitonic_sort_desc_2048(key, tid);

    // stage boxes in sorted order (row stride 336B is 16B aligned -> float4 ok)
    for (int n = tid; n < NN; n += 256) {
        u32 orig = 0xFFFFFFFFu - (u32)(key[n] & 0xFFFFFFFFu);
        sbox[n] = *(const float4*)(xb + (size_t)orig * ROW);
    }
    if (tid == 0) { s_i = 0; s_kept = 0; s_done = 0; }
    __syncthreads();

    // greedy NMS with early exit at 200 kept or score <= threshold
    for (;;) {
        if (tid == 0) {
            if (s_kept >= OUT_K) {
                s_done = 1;
            } else {
                int i = s_i;
                while (i < NN) {
                    float sc = __uint_as_float((u32)(key[i] >> 32));
                    if (!(sc > SCORE_T)) { i = NN; break; }   // sorted desc: nothing later qualifies
                    if (keep[i]) break;
                    i++;
                }
                if (i >= NN) {
                    s_done = 1;
                } else {
                    s_cur = i;
                    s_i = i + 1;
                    s_curbox = sbox[i];
                    s_slots[s_kept] = i;
                    s_kept++;
                    if (s_kept >= OUT_K) s_done = 1;  // 200th kept needs no suppression pass
                }
            }
        }
        __syncthreads();
        if (s_done) break;

        const int i = s_cur;
        const float4 bi = s_curbox;
        const float ai = __fmul_rn(__fsub_rn(bi.z, bi.x), __fsub_rn(bi.w, bi.y));
        for (int j = i + 1 + tid; j < NN; j += 256) {
            if (keep[j]) {
                float4 bj = sbox[j];
                float ltx = fmaxf(bi.x, bj.x);
                float lty = fmaxf(bi.y, bj.y);
                float rbx = fminf(bi.z, bj.z);
                float rby = fminf(bi.w, bj.w);
                float w = fmaxf(__fsub_rn(rbx, ltx), 0.0f);
                float h = fmaxf(__fsub_rn(rby, lty), 0.0f);
                float inter = __fmul_rn(w, h);
                float aj = __fmul_rn(__fsub_rn(bj.z, bj.x), __fsub_rn(bj.w, bj.y));
                float uni = __fsub_rn(__fadd_rn(ai, aj), inter);
                float iou = __fdiv_rn(inter, fmaxf(uni, 1e-8f));
                if (iou > IOU_T) keep[j] = 0;
            }
        }
        __syncthreads();
    }

    // emit exactly 200 candidate slots per (b,c); empty slots -> key 0 (invalid)
    const int base = (b * NC + c) * OUT_K;
    for (int s = tid; s < OUT_K; s += 256) {
        u64 ok = 0ULL; u32 oi = 0u;
        if (s < s_kept) {
            int i = s_slots[s];
            u64 kk = key[i];
            u32 scbits = (u32)(kk >> 32);
            // tie-break index (c*200+slot) preserves reference (c*N+pos) ordering
            ok = ((u64)scbits << 32) | (u64)(0xFFFFFFFFu - (u32)(c * OUT_K + s));
            oi = 0xFFFFFFFFu - (u32)(kk & 0xFFFFFFFFu);   // original box index
        }
        cand_key[base + s] = ok;
        cand_idx[base + s] = oi;
    }
}

// ---- Kernel B: one block per batch -> top-200 of 16000 sorted-desc keys ----
__global__ __launch_bounds__(256) void topk_kernel(
        const float* __restrict__ x, const u64* __restrict__ cand_key,
        const u32* __restrict__ cand_idx, float* __restrict__ out) {
    const int b = blockIdx.x;
    const int tid = threadIdx.x;
    const int TOT = NC * OUT_K;  // 16000

    __shared__ u64 A[2048];
    __shared__ u64 Bb[2048];

    const u64* ck = cand_key + (size_t)b * TOT;

    for (int i = tid; i < 2048; i += 256) A[i] = (i < TOT) ? ck[i] : 0ULL;
    __syncthreads();
    bitonic_sort_desc_2048(A, tid);

    for (int chunk = 1; chunk < 8; chunk++) {
        const int off = chunk * 2048;
        for (int i = tid; i < 2048; i += 256) {
            int s = off + i;
            Bb[i] = (s < TOT) ? ck[s] : 0ULL;
        }
        __syncthreads();
        bitonic_sort_desc_2048(Bb, tid);
        // max-merge: A keeps top-2048 of A∪Bb, result is bitonic
        for (int i = tid; i < 2048; i += 256) {
            u64 xv = A[i], yv = Bb[2047 - i];
            A[i] = (xv > yv) ? xv : yv;
        }
        __syncthreads();
        bitonic_merge_desc_2048(A, tid);
    }

    const float* xb = x + (size_t)b * NN * ROW;
    for (int k = tid; k < OUT_K; k += 256) {
        u64 kk = A[k];
        float* o = out + ((size_t)b * OUT_K + k) * 6;
        if (kk == 0ULL) {
            o[0] = 0.f; o[1] = 0.f; o[2] = 0.f; o[3] = 0.f; o[4] = 0.f; o[5] = 0.f;
        } else {
            u32 flat = 0xFFFFFFFFu - (u32)(kk & 0xFFFFFFFFu);  // c*200 + slot
            int cls = flat / OUT_K;
            u32 n = cand_idx[(size_t)b * TOT + flat];
            float sc = __uint_as_float((u32)(kk >> 32));
            float4 bx = *(const float4*)(xb + (size_t)n * ROW);
            o[0] = (float)cls;
            o[1] = sc;
            o[2] = fminf(fmaxf(bx.x, 0.0f), 1.0f);
            o[3] = fminf(fmaxf(bx.y, 0.0f), 1.0f);
            o[4] = fminf(fmaxf(bx.z, 0.0f), 1.0f);
            o[5] = fminf(fmaxf(bx.w, 0.0f), 1.0f);
        }
    }
}

extern "C" void kernel_launch(void* const* d_in, const int* in_sizes, int n_in,
                              void* d_out, int out_size, void* d_ws, size_t ws_size,
                              hipStream_t stream) {
    const float* x = (const float*)d_in[0];
    float* out = (float*)d_out;
    // workspace: 8*80*200 u64 keys (1,024,000 B) + 8*80*200 u32 idx (512,000 B)
    u64* cand_key = (u64*)d_ws;
    u32* cand_idx = (u32*)((char*)d_ws + (size_t)NB * NC * OUT_K * sizeof(u64));
    nms_class_kernel<<<NB * NC, 256, 0, stream>>>(x, cand_key, cand_idx);
    topk_kernel<<<NB, 256, 0, stream>>>(x, cand_key, cand_idx, out);
}

// Round 2
// 797.359 us; speedup vs baseline: 2.0917x; 2.0917x over previous
//
#include <hip/hip_runtime.h>
#include <stdint.h>

typedef unsigned long long u64;
typedef unsigned int u32;

#define NB 8
#define NN 2048
#define NC 80
#define ROW 84
#define OUT_K 200
#define IOU_T 0.5f
#define SCORE_T 0.01f

// ---- 256-thread bitonic sort, descending, 2048 u64 in LDS ----
__device__ __forceinline__ void bitonic_sort_desc_2048_b256(u64* a, int tid) {
    for (int k = 2; k <= 2048; k <<= 1) {
        for (int j = k >> 1; j > 0; j >>= 1) {
            for (int i = tid; i < 2048; i += 256) {
                int ixj = i ^ j;
                if (ixj > i) {
                    u64 x = a[i], y = a[ixj];
                    bool up = ((i & k) == 0);
                    if (up ? (x < y) : (x > y)) { a[i] = y; a[ixj] = x; }
                }
            }
            __syncthreads();
        }
    }
}

// ---- Kernel A: ONE WAVE per (batch, class). No barriers in greedy loop. ----
__global__ __launch_bounds__(64) void nms_wave_kernel(
        const float* __restrict__ x, u64* __restrict__ cand_key,
        u32* __restrict__ cand_idx) {
    const int bc = blockIdx.x;
    const int b = bc / NC;
    const int c = bc % NC;
    const int lane = threadIdx.x;

    __shared__ u64 key[NN];        // (score_bits<<32) | (0xFFFFFFFF - orig_idx)
    __shared__ float4 sbox[NN];    // boxes in sorted order
    __shared__ int slots[OUT_K];   // sorted-position of each kept box

    const float* xb = x + (size_t)b * NN * ROW;

    // build keys
    #pragma unroll
    for (int w = 0; w < 32; w++) {
        int n = w * 64 + lane;
        float sc = xb[n * ROW + 4 + c];          // scores >= 0 -> bits monotone
        key[n] = ((u64)__float_as_uint(sc) << 32) | (u64)(0xFFFFFFFFu - (u32)n);
    }
    __syncthreads();   // single-wave block: ~free

    // single-wave bitonic sort (descending)
    for (int k = 2; k <= NN; k <<= 1) {
        for (int j = k >> 1; j > 0; j >>= 1) {
            #pragma unroll
            for (int w = 0; w < 32; w++) {
                int t = w * 64 + lane;
                int ixj = t ^ j;
                if (ixj > t) {
                    u64 a0 = key[t], a1 = key[ixj];
                    bool up = ((t & k) == 0);
                    if (up ? (a0 < a1) : (a0 > a1)) { key[t] = a1; key[ixj] = a0; }
                }
            }
            __syncthreads();
        }
    }

    // count valid (score > thr; sorted desc => prefix), gather boxes into
    // registers (for the unrolled overlap test) and LDS (for random access)
    int nv = 0;
    float4 rb[32];
    #pragma unroll
    for (int w = 0; w < 32; w++) {
        int n = w * 64 + lane;
        u64 kk = key[n];
        float sc = __uint_as_float((u32)(kk >> 32));
        nv += __popcll(__ballot(sc > SCORE_T));
        u32 orig = 0xFFFFFFFFu - (u32)(kk & 0xFFFFFFFFu);
        float4 bx = *(const float4*)(xb + (size_t)orig * ROW);  // 336B stride, 16B aligned
        rb[w] = bx;
        sbox[n] = bx;
    }
    __syncthreads();

    // alive mask: lane owns sorted positions j = w*64+lane (bit w)
    u32 mask = 0;
    #pragma unroll
    for (int w = 0; w < 32; w++) mask |= ((u32)((w * 64 + lane) < nv)) << w;

    int kept = 0;
    for (;;) {
        // next survivor = global min alive sorted-position (register min-reduce)
        int my = mask ? (__builtin_ctz(mask) * 64 + lane) : 0x7FFFFFFF;
        #pragma unroll
        for (int off = 32; off > 0; off >>= 1) {
            int o = __shfl_xor(my, off, 64);
            my = my < o ? my : o;
        }
        if (my == 0x7FFFFFFF) break;
        const int i = my;
        if ((i & 63) == lane) mask &= ~(1u << (i >> 6));   // owner clears
        if (lane == 0) slots[kept] = i;                     // write-only in loop
        kept++;
        if (kept >= OUT_K) break;   // 200th kept needs no suppression pass

        // current box: same-address LDS read = broadcast
        float4 bi = sbox[i];
        float ai = __fmul_rn(__fsub_rn(bi.z, bi.x), __fsub_rn(bi.w, bi.y));

        // phase A: cheap conservative overlap test vs register-held boxes.
        // inter>0  <=>  max(x1)<min(x2) && max(y1)<min(y2)  (exact: min/max/cmp)
        u32 ov = 0;
        #pragma unroll
        for (int w = 0; w < 32; w++) {
            float4 bj = rb[w];
            bool o = (fmaxf(bi.x, bj.x) < fminf(bi.z, bj.z)) &
                     (fmaxf(bi.y, bj.y) < fminf(bi.w, bj.w));
            ov |= ((u32)o) << w;
        }
        ov &= mask;

        // phase B: exact IoU (reference op order) only on overlapping bits
        while (ov) {
            int w = __builtin_ctz(ov);
            ov &= ov - 1;
            float4 bj = sbox[w * 64 + lane];
            float ltx = fmaxf(bi.x, bj.x);
            float lty = fmaxf(bi.y, bj.y);
            float rbx = fminf(bi.z, bj.z);
            float rby = fminf(bi.w, bj.w);
            float ww = fmaxf(__fsub_rn(rbx, ltx), 0.0f);
            float hh = fmaxf(__fsub_rn(rby, lty), 0.0f);
            float inter = __fmul_rn(ww, hh);
            float aj = __fmul_rn(__fsub_rn(bj.z, bj.x), __fsub_rn(bj.w, bj.y));
            float uni = __fsub_rn(__fadd_rn(ai, aj), inter);
            float iou = __fdiv_rn(inter, fmaxf(uni, 1e-8f));
            if (iou > IOU_T) mask &= ~(1u << w);
        }
    }

    __syncthreads();   // make lane0's slots[] visible to all lanes

    // emit 200 candidate slots per (b,c); empty -> key 0 (invalid)
    const int base = (b * NC + c) * OUT_K;
    for (int s = lane; s < OUT_K; s += 64) {
        u64 ok = 0ULL; u32 oi = 0u;
        if (s < kept) {
            int i2 = slots[s];
            u64 kk = key[i2];
            // tie-break index (c*200+slot) preserves reference (c*N+pos) order
            ok = (kk & 0xFFFFFFFF00000000ULL) |
                 (u64)(0xFFFFFFFFu - (u32)(c * OUT_K + s));
            oi = 0xFFFFFFFFu - (u32)(kk & 0xFFFFFFFFu);
        }
        cand_key[base + s] = ok;
        cand_idx[base + s] = oi;
    }
}

// ---- Kernel B1: 64 blocks; sort one 2000-entry chunk, emit top-256 ----
__global__ __launch_bounds__(256) void topk_stage1(
        const u64* __restrict__ cand_key, u64* __restrict__ ws2) {
    const int g = blockIdx.x;
    const int b = g >> 3, ch = g & 7;
    const int tid = threadIdx.x;
    __shared__ u64 A[2048];
    const u64* src = cand_key + (size_t)b * (NC * OUT_K) + (size_t)ch * 2000;
    for (int i = tid; i < 2048; i += 256) A[i] = (i < 2000) ? src[i] : 0ULL;
    __syncthreads();
    bitonic_sort_desc_2048_b256(A, tid);
    // top-256 is lossless for a global top-200 merge
    ws2[(size_t)g * 256 + tid] = A[tid];
}

// ---- Kernel B2: 8 blocks; sort 8x256 survivors, decode top-200 ----
__global__ __launch_bounds__(256) void topk_stage2(
        const float* __restrict__ x, const u64* __restrict__ ws2,
        const u32* __restrict__ cand_idx, float* __restrict__ out) {
    const int b = blockIdx.x;
    const int tid = threadIdx.x;
    __shared__ u64 A[2048];
    for (int i = tid; i < 2048; i += 256) A[i] = ws2[(size_t)b * 2048 + i];
    __syncthreads();
    bitonic_sort_desc_2048_b256(A, tid);

    const float* xb = x + (size_t)b * NN * ROW;
    for (int k = tid; k < OUT_K; k += 256) {
        u64 kk = A[k];
        float* o = out + ((size_t)b * OUT_K + k) * 6;
        if (kk == 0ULL) {
            o[0] = 0.f; o[1] = 0.f; o[2] = 0.f; o[3] = 0.f; o[4] = 0.f; o[5] = 0.f;
        } else {
            u32 flat = 0xFFFFFFFFu - (u32)(kk & 0xFFFFFFFFu);  // c*200 + slot
            int cls = flat / OUT_K;
            u32 n = cand_idx[(size_t)b * (NC * OUT_K) + flat];
            float sc = __uint_as_float((u32)(kk >> 32));
            float4 bx = *(const float4*)(xb + (size_t)n * ROW);
            o[0] = (float)cls;
            o[1] = sc;
            o[2] = fminf(fmaxf(bx.x, 0.0f), 1.0f);
            o[3] = fminf(fmaxf(bx.y, 0.0f), 1.0f);
            o[4] = fminf(fmaxf(bx.z, 0.0f), 1.0f);
            o[5] = fminf(fmaxf(bx.w, 0.0f), 1.0f);
        }
    }
}

extern "C" void kernel_launch(void* const* d_in, const int* in_sizes, int n_in,
                              void* d_out, int out_size, void* d_ws, size_t ws_size,
                              hipStream_t stream) {
    const float* x = (const float*)d_in[0];
    float* out = (float*)d_out;
    // ws layout: cand_key 8*16000*8 = 1,024,000 B
    //            cand_idx 8*16000*4 =   512,000 B
    //            ws2      64*256*8  =   131,072 B   (total ~1.67 MB)
    u64* cand_key = (u64*)d_ws;
    u32* cand_idx = (u32*)((char*)d_ws + (size_t)NB * NC * OUT_K * sizeof(u64));
    u64* ws2 = (u64*)((char*)d_ws + (size_t)NB * NC * OUT_K * (sizeof(u64) + sizeof(u32)));
    nms_wave_kernel<<<NB * NC, 64, 0, stream>>>(x, cand_key, cand_idx);
    topk_stage1<<<NB * 8, 256, 0, stream>>>(cand_key, ws2);
    topk_stage2<<<NB, 256, 0, stream>>>(x, ws2, cand_idx, out);
}

// Round 3
// 366.691 us; speedup vs baseline: 4.5484x; 2.1745x over previous
//
#include <hip/hip_runtime.h>
#include <stdint.h>

typedef unsigned long long u64;
typedef unsigned int u32;
typedef unsigned short u16;

#define NB 8
#define NN 2048
#define NC 80
#define ROW 84
#define OUT_K 200
#define IOU_T 0.5f
#define SCORE_T 0.01f
#define POS_INF 0x7FFFFFFF

// ---- 256-thread bitonic sort, descending, 2048 u64 in LDS ----
__device__ __forceinline__ void bitonic_sort_desc_2048_b256(u64* a, int tid) {
    for (int k = 2; k <= 2048; k <<= 1) {
        for (int j = k >> 1; j > 0; j >>= 1) {
            for (int i = tid; i < 2048; i += 256) {
                int ixj = i ^ j;
                if (ixj > i) {
                    u64 x = a[i], y = a[ixj];
                    bool up = ((i & k) == 0);
                    if (up ? (x < y) : (x > y)) { a[i] = y; a[ixj] = x; }
                }
            }
            __syncthreads();
        }
    }
}

// ---- Kernel A: 4 waves per (batch, class); registers-only suppression ----
__global__ __launch_bounds__(256) void nms_kernel(
        const float* __restrict__ x, u64* __restrict__ cand_key,
        u16* __restrict__ cand_idx) {
    const int bc = blockIdx.x;
    const int b = bc / NC;
    const int c = bc % NC;
    const int tid = threadIdx.x;
    const int lane = tid & 63;
    const int wv = tid >> 6;

    __shared__ u64 key[NN];        // (score_bits<<32) | (0xFFFFFFFF - orig_idx)
    __shared__ float4 sbox[NN];    // boxes in sorted order
    __shared__ int slots[OUT_K];
    __shared__ int s_min[4];

    const float* xb = x + (size_t)b * NN * ROW;

    // build keys (score desc, index asc)
    #pragma unroll
    for (int w = 0; w < 8; w++) {
        int n = w * 256 + tid;
        float sc = xb[n * ROW + 4 + c];
        key[n] = ((u64)__float_as_uint(sc) << 32) | (u64)(0xFFFFFFFFu - (u32)n);
    }
    __syncthreads();
    bitonic_sort_desc_2048_b256(key, tid);

    // stage boxes in sorted order (row stride 336B is 16B-aligned -> float4)
    #pragma unroll
    for (int w = 0; w < 8; w++) {
        int n = w * 256 + tid;
        u32 orig = 0xFFFFFFFFu - (u32)(key[n] & 0xFFFFFFFFu);
        sbox[n] = *(const float4*)(xb + (size_t)orig * ROW);
    }
    __syncthreads();

    // wave wv owns sorted positions wv*512 + w*64 + lane, w in [0,8)
    float x1[8], y1[8], x2[8], y2[8], ar[8];
    u32 mask = 0;
    #pragma unroll
    for (int w = 0; w < 8; w++) {
        int n = wv * 512 + w * 64 + lane;
        float4 bx = sbox[n];
        x1[w] = bx.x; y1[w] = bx.y; x2[w] = bx.z; y2[w] = bx.w;
        // exact reference-order area
        ar[w] = __fmul_rn(__fsub_rn(bx.z, bx.x), __fsub_rn(bx.w, bx.y));
        float sc = __uint_as_float((u32)(key[n] >> 32));
        mask |= ((u32)(sc > SCORE_T)) << w;
    }

    int kept = 0;
    for (;;) {
        // per-wave min alive position
        int my = mask ? ((wv * 8 + __builtin_ctz(mask)) * 64 + lane) : POS_INF;
        #pragma unroll
        for (int off = 32; off > 0; off >>= 1) {
            int o = __shfl_xor(my, off, 64);
            my = my < o ? my : o;
        }
        if (lane == 0) s_min[wv] = my;
        __syncthreads();
        int i0 = s_min[0], i1 = s_min[1], i2 = s_min[2], i3 = s_min[3];
        int i = min(min(i0, i1), min(i2, i3));
        if (i == POS_INF) break;

        // owner clears its bit
        int wg = i >> 6;               // global word
        if ((wg >> 3) == wv && (i & 63) == lane) mask &= ~(1u << (wg & 7));
        if (tid == 0) slots[kept] = i;
        kept++;
        if (kept >= OUT_K) break;      // 200th kept needs no suppression pass

        // broadcast current box (same-address LDS read)
        float4 bi = sbox[i];
        float ai = __fmul_rn(__fsub_rn(bi.z, bi.x), __fsub_rn(bi.w, bi.y));

        // exact suppression test on this wave's 8 register-resident words
        #pragma unroll
        for (int w = 0; w < 8; w++) {
            float ltx = fmaxf(bi.x, x1[w]);
            float lty = fmaxf(bi.y, y1[w]);
            float rbx = fminf(bi.z, x2[w]);
            float rby = fminf(bi.w, y2[w]);
            float wd = fmaxf(__fsub_rn(rbx, ltx), 0.0f);
            float hd = fmaxf(__fsub_rn(rby, lty), 0.0f);
            float inter = __fmul_rn(wd, hd);
            float uni = __fsub_rn(__fadd_rn(ai, ar[w]), inter);
            float m = fmaxf(uni, 1e-8f);
            float d2 = __fmul_rn(2.0f, inter);   // exact scaling
            bool sup = d2 > m;                    // == (inter/m > 0.5) exactly
            // fdiv-rounding boundary guard: disagreement only possible when
            // d2/m in (1, 1+2^-24]; margin 1.2e-7 covers it with 2x slack
            if (sup && (__fsub_rn(d2, m) <= __fmul_rn(m, 1.2e-7f)))
                sup = __fdiv_rn(inter, m) > IOU_T;   // ~never taken
            mask &= ~(((u32)sup) << w);
        }
        __syncthreads();   // s_min reads done before next iteration's writes
    }
    __syncthreads();

    // emit 200 candidate slots per (b,c); empty -> key 0 (invalid)
    const int base = (b * NC + c) * OUT_K;
    if (tid < OUT_K) {
        u64 ok = 0ULL; u16 oi = 0;
        if (tid < kept) {
            int ii = slots[tid];
            u64 kk = key[ii];
            // tie-break index (c*200+slot) preserves reference (c*N+pos) order
            ok = (kk & 0xFFFFFFFF00000000ULL) |
                 (u64)(0xFFFFFFFFu - (u32)(c * OUT_K + tid));
            oi = (u16)(0xFFFFFFFFu - (u32)(kk & 0xFFFFFFFFu));
        }
        cand_key[base + tid] = ok;
        cand_idx[base + tid] = oi;
    }
}

// merge tree over `nruns` desc-sorted 256-runs in LDS (stride starts at 256);
// leaves top-256 of all runs, sorted desc, at A[0..255]
__device__ __forceinline__ void merge_runs_256(u64* A, int nruns, int tid) {
    int S = 256;
    for (int nr = nruns; nr > 1; nr >>= 1) {
        int npair = nr >> 1;
        // max-combine: pair p -> run at offset p*2S (in-place safe: second
        // halves are read-only, first-half slot read+written by same thread)
        for (int t = tid; t < npair * 256; t += 256) {
            int p = t >> 8, pos = t & 255;
            u64 xv = A[p * 2 * S + pos];
            u64 yv = A[p * 2 * S + S + 255 - pos];
            A[p * 2 * S + pos] = xv > yv ? xv : yv;
        }
        __syncthreads();
        // bitonic merge each 256 result run, descending
        for (int j = 128; j > 0; j >>= 1) {
            for (int t = tid; t < npair * 128; t += 256) {
                int p = t >> 7, r = t & 127;
                int low = r & (j - 1), high = (r & ~(j - 1)) << 1;
                int idx = p * 2 * S + (high | low);
                u64 a0 = A[idx], a1 = A[idx + j];
                if (a0 < a1) { A[idx] = a1; A[idx + j] = a0; }
            }
            __syncthreads();
        }
        S <<= 1;
    }
}

// ---- Kernel B1: 80 blocks; merge 8 class-runs of 200 -> top-256 ----
__global__ __launch_bounds__(256) void topk_stage1(
        const u64* __restrict__ cand_key, u64* __restrict__ ws2) {
    const int b = blockIdx.x / 10, ch = blockIdx.x % 10;
    const int tid = threadIdx.x;
    __shared__ u64 A[2048];
    const u64* src = cand_key + (size_t)b * (NC * OUT_K) + (size_t)ch * 8 * OUT_K;
    for (int i = tid; i < 2048; i += 256) {
        int run = i >> 8, pos = i & 255;
        A[i] = (pos < OUT_K) ? src[run * OUT_K + pos] : 0ULL;
    }
    __syncthreads();
    merge_runs_256(A, 8, tid);
    ws2[(size_t)b * 2560 + ch * 256 + tid] = A[tid];
}

// ---- Kernel B2: 8 blocks; merge 10 runs of 256 (pad to 16) -> top-200 ----
__global__ __launch_bounds__(256) void topk_stage2(
        const float* __restrict__ x, const u64* __restrict__ ws2,
        const u16* __restrict__ cand_idx, float* __restrict__ out) {
    const int b = blockIdx.x;
    const int tid = threadIdx.x;
    __shared__ u64 A[4096];
    for (int i = tid; i < 4096; i += 256)
        A[i] = (i < 2560) ? ws2[(size_t)b * 2560 + i] : 0ULL;
    __syncthreads();
    merge_runs_256(A, 16, tid);

    const float* xb = x + (size_t)b * NN * ROW;
    if (tid < OUT_K) {
        u64 kk = A[tid];
        float* o = out + ((size_t)b * OUT_K + tid) * 6;
        if (kk == 0ULL) {
            o[0] = 0.f; o[1] = 0.f; o[2] = 0.f; o[3] = 0.f; o[4] = 0.f; o[5] = 0.f;
        } else {
            u32 flat = 0xFFFFFFFFu - (u32)(kk & 0xFFFFFFFFu);  // c*200 + slot
            int cls = flat / OUT_K;
            u32 n = cand_idx[(size_t)b * (NC * OUT_K) + flat];
            float sc = __uint_as_float((u32)(kk >> 32));
            float4 bx = *(const float4*)(xb + (size_t)n * ROW);
            o[0] = (float)cls;
            o[1] = sc;
            o[2] = fminf(fmaxf(bx.x, 0.0f), 1.0f);
            o[3] = fminf(fmaxf(bx.y, 0.0f), 1.0f);
            o[4] = fminf(fmaxf(bx.z, 0.0f), 1.0f);
            o[5] = fminf(fmaxf(bx.w, 0.0f), 1.0f);
        }
    }
}

extern "C" void kernel_launch(void* const* d_in, const int* in_sizes, int n_in,
                              void* d_out, int out_size, void* d_ws, size_t ws_size,
                              hipStream_t stream) {
    const float* x = (const float*)d_in[0];
    float* out = (float*)d_out;
    // ws layout: cand_key 8*16000*8 = 1,024,000 B
    //            cand_idx 8*16000*2 =   256,000 B
    //            ws2      8*2560*8  =   163,840 B   (total ~1.44 MB)
    u64* cand_key = (u64*)d_ws;
    u16* cand_idx = (u16*)((char*)d_ws + (size_t)NB * NC * OUT_K * sizeof(u64));
    u64* ws2 = (u64*)((char*)d_ws + (size_t)NB * NC * OUT_K * (sizeof(u64) + sizeof(u16)));
    nms_kernel<<<NB * NC, 256, 0, stream>>>(x, cand_key, cand_idx);
    topk_stage1<<<NB * 10, 256, 0, stream>>>(cand_key, ws2);
    topk_stage2<<<NB, 256, 0, stream>>>(x, ws2, cand_idx, out);
}

// Round 4
// 241.035 us; speedup vs baseline: 6.9196x; 1.5213x over previous
//
#include <hip/hip_runtime.h>
#include <stdint.h>

typedef unsigned long long u64;
typedef unsigned int u32;
typedef unsigned short u16;

#define NB 8
#define NN 2048
#define NC 80
#define ROW 84
#define OUT_K 200
#define IOU_T 0.5f
#define SCORE_T 0.01f

// ---- compare-exchange, descending network, direction from global index ----
__device__ __forceinline__ void ce_desc(u64* a, int i, int j, int k) {
    u64 a0 = a[i], a1 = a[i + j];
    bool up = ((i & k) == 0);
    if (up ? (a0 < a1) : (a0 > a1)) { a[i] = a1; a[i + j] = a0; }
}

// wave-local rounds on a 512-elem segment (4 CE/lane/round), j<=256
__device__ __forceinline__ void wave_rounds512(u64* a, int base, int k, int jhi, int lane) {
    for (int j = jhi; j > 0; j >>= 1) {
        #pragma unroll
        for (int p = 0; p < 4; p++) {
            int r = lane + p * 64;
            int low = r & (j - 1);
            int high = (r & ~(j - 1)) << 1;
            ce_desc(a, base + (high | low), j, k);
        }
        __builtin_amdgcn_wave_barrier();   // order stages; DS is in-order per wave
    }
}

// wave-local rounds on a 256-elem segment (2 CE/lane/round), j<=128
__device__ __forceinline__ void wave_rounds256(u64* a, int base, int k, int jhi, int lane) {
    for (int j = jhi; j > 0; j >>= 1) {
        #pragma unroll
        for (int p = 0; p < 2; p++) {
            int r = lane + p * 64;
            int low = r & (j - 1);
            int high = (r & ~(j - 1)) << 1;
            ce_desc(a, base + (high | low), j, k);
        }
        __builtin_amdgcn_wave_barrier();
    }
}

// exact reference-order IoU > 0.5 test (identical to passing round-3 logic)
__device__ __forceinline__ bool iou_gt_half(float4 a, float aa, float4 b, float ab) {
    float ltx = fmaxf(a.x, b.x);
    float lty = fmaxf(a.y, b.y);
    float rbx = fminf(a.z, b.z);
    float rby = fminf(a.w, b.w);
    float wd = fmaxf(__fsub_rn(rbx, ltx), 0.0f);
    float hd = fmaxf(__fsub_rn(rby, lty), 0.0f);
    float inter = __fmul_rn(wd, hd);
    float uni = __fsub_rn(__fadd_rn(aa, ab), inter);
    float m = fmaxf(uni, 1e-8f);
    float d2 = __fmul_rn(2.0f, inter);     // exact scaling
    bool sup = d2 > m;                      // == (inter/m > 0.5) exactly
    if (sup && (__fsub_rn(d2, m) <= __fmul_rn(m, 1.2e-7f)))
        sup = __fdiv_rn(inter, m) > IOU_T;  // fdiv boundary guard, ~never taken
    return sup;
}

// ---- Kernel A: per (b,c): 4-wave hybrid sort, then single-wave chunked greedy ----
__global__ __launch_bounds__(256) void nms_kernel(
        const float* __restrict__ x, u64* __restrict__ cand_key,
        u16* __restrict__ cand_idx) {
    const int bc = blockIdx.x;
    const int b = bc / NC;
    const int c = bc % NC;
    const int tid = threadIdx.x;
    const int lane = tid & 63;
    const int wv = tid >> 6;
    const int base = wv * 512;

    __shared__ u64 key[NN];            // (score_bits<<32) | (0xFFFFFFFF - orig_idx)
    __shared__ float4 kept_box[OUT_K];
    __shared__ float kept_area[OUT_K];
    __shared__ u64 kept_key[OUT_K];
    __shared__ int s_kept;

    const float* xb = x + (size_t)b * NN * ROW;

    // build keys (score desc, index asc)
    #pragma unroll
    for (int w = 0; w < 8; w++) {
        int n = w * 256 + tid;
        float sc = xb[n * ROW + 4 + c];
        key[n] = ((u64)__float_as_uint(sc) << 32) | (u64)(0xFFFFFFFFu - (u32)n);
    }
    __syncthreads();

    // hybrid bitonic sort of 2048, descending.
    // stages k=2..512 (j<=256): fully wave-local on own 512-segment
    for (int k = 2; k <= 512; k <<= 1)
        wave_rounds512(key, base, k, k >> 1, lane);
    __syncthreads();
    // k=1024: j=512 crosses segments
    #pragma unroll
    for (int p = 0; p < 4; p++) {
        int r = tid + p * 256;
        int low = r & 511, high = (r & ~511) << 1;
        ce_desc(key, high | low, 512, 1024);
    }
    __syncthreads();
    wave_rounds512(key, base, 1024, 256, lane);
    __syncthreads();
    // k=2048: j=1024, 512 cross; rest local
    #pragma unroll
    for (int p = 0; p < 4; p++) {
        int r = tid + p * 256;
        int low = r & 1023, high = (r & ~1023) << 1;
        ce_desc(key, high | low, 1024, 2048);
    }
    __syncthreads();
    #pragma unroll
    for (int p = 0; p < 4; p++) {
        int r = tid + p * 256;
        int low = r & 511, high = (r & ~511) << 1;
        ce_desc(key, high | low, 512, 2048);
    }
    __syncthreads();
    wave_rounds512(key, base, 2048, 256, lane);
    __syncthreads();

    // ---- single-wave chunked greedy (wave 0), no barriers ----
    if (wv == 0) {
        int kept = 0;
        bool done = false;
        for (int ch = 0; ch < 32 && !done; ch++) {
            int n = ch * 64 + lane;
            u64 mykey = key[n];
            float sc = __uint_as_float((u32)(mykey >> 32));
            bool valid = sc > SCORE_T;
            u64 vball = __ballot(valid);
            if (vball == 0ULL) break;

            u32 orig = 0xFFFFFFFFu - (u32)(mykey & 0xFFFFFFFFu);
            float4 bx = *(const float4*)(xb + (size_t)orig * ROW);
            float ar = __fmul_rn(__fsub_rn(bx.z, bx.x), __fsub_rn(bx.w, bx.y));

            // data-parallel test vs kept list (LDS broadcast reads)
            bool alive_f = valid;
            for (int t = 0; t < kept; t++) {
                float4 kb = kept_box[t];
                float ka = kept_area[t];
                if (alive_f && iou_gt_half(bx, ar, kb, ka)) alive_f = false;
            }
            u64 alive = __ballot(alive_f);

            // wave-serial scan: one step per KEPT box
            while (alive) {
                int bsel = __builtin_ctzll(alive);
                if (lane == bsel) {
                    kept_key[kept] = mykey;
                    kept_box[kept] = bx;
                    kept_area[kept] = ar;
                }
                kept++;
                if (kept >= OUT_K) { done = true; break; }
                alive &= alive - 1;               // clear bsel
                if (!alive) break;
                float px1 = __shfl(bx.x, bsel);
                float py1 = __shfl(bx.y, bsel);
                float px2 = __shfl(bx.z, bsel);
                float py2 = __shfl(bx.w, bsel);
                float pa  = __shfl(ar, bsel);
                float4 pb = make_float4(px1, py1, px2, py2);
                bool sup = iou_gt_half(bx, ar, pb, pa);
                alive &= ~__ballot(sup);
            }
            __builtin_amdgcn_wave_barrier();      // kept_* writes ordered vs next chunk reads
            if (__popcll(vball) < 64) break;      // sorted: nothing valid beyond
        }
        if (lane == 0) s_kept = kept;
    }
    __syncthreads();

    // emit 200 candidate slots per (b,c); empty -> key 0 (invalid)
    const int base_o = (b * NC + c) * OUT_K;
    if (tid < OUT_K) {
        u64 ok = 0ULL; u16 oi = 0;
        if (tid < s_kept) {
            u64 kk = kept_key[tid];
            // tie-break index (c*200+slot) preserves reference (c*N+pos) order
            ok = (kk & 0xFFFFFFFF00000000ULL) |
                 (u64)(0xFFFFFFFFu - (u32)(c * OUT_K + tid));
            oi = (u16)(0xFFFFFFFFu - (u32)(kk & 0xFFFFFFFFu));
        }
        cand_key[base_o + tid] = ok;
        cand_idx[base_o + tid] = oi;
    }
}

// ---- Kernel B: one block per batch; histogram-select + sort-512 + decode ----
__device__ __forceinline__ u32 key_bin(u64 kk) {
    u32 sb = (u32)(kk >> 32);
    int bi = (int)(sb >> 13) - 122880;   // 0x3C000000>>13; scores<2^-7 clamp to 0
    return (u32)min(max(bi, 0), 8191);
}

__global__ __launch_bounds__(256) void topk_kernel(
        const float* __restrict__ x, const u64* __restrict__ cand_key,
        const u16* __restrict__ cand_idx, float* __restrict__ out) {
    const int b = blockIdx.x;
    const int tid = threadIdx.x;
    const int lane = tid & 63;
    const int wv = tid >> 6;
    const int TOT = NC * OUT_K;  // 16000

    __shared__ u32 hist[8192];   // 32 KB
    __shared__ u32 tsum[256];
    __shared__ u64 comp[512];
    __shared__ u32 s_cnt, s_thr;

    const u64* ck = cand_key + (size_t)b * TOT;

    for (int i = tid; i < 8192; i += 256) hist[i] = 0;
    if (tid == 0) { s_cnt = 0; s_thr = 0; }
    __syncthreads();

    // histogram of nonzero keys
    for (int kq = 0; kq < 63; kq++) {
        int i = tid + kq * 256;
        if (i < TOT) {
            u64 kk = ck[i];
            if (kk) atomicAdd(&hist[key_bin(kk)], 1);
        }
    }
    __syncthreads();

    // per-thread totals over 32 contiguous bins, then reverse-exclusive scan
    {
        u32 loc = 0;
        #pragma unroll 8
        for (int q = 0; q < 32; q++) loc += hist[tid * 32 + q];
        tsum[tid] = loc;
    }
    __syncthreads();
    if (tid == 0) {
        u32 run = 0;
        for (int t = 255; t >= 0; t--) { u32 v = tsum[t]; tsum[t] = run; run += v; }
    }
    __syncthreads();
    // find threshold bin: highest bin where suffix-count >= OUT_K
    {
        u32 cum = tsum[tid];
        for (int q = 31; q >= 0; q--) {
            u32 cnt = hist[tid * 32 + q];
            if (cum < OUT_K && cum + cnt >= OUT_K) s_thr = (u32)(tid * 32 + q);
            cum += cnt;
        }
    }
    __syncthreads();
    const u32 thr = s_thr;

    // compact qualifying keys (bin >= thr is an exact superset of top-200)
    for (int kq = 0; kq < 63; kq++) {
        int i = tid + kq * 256;
        if (i < TOT) {
            u64 kk = ck[i];
            if (kk && key_bin(kk) >= thr) {
                u32 p = atomicAdd(&s_cnt, 1);
                if (p < 512) comp[p] = kk;
            }
        }
    }
    __syncthreads();
    const u32 cnt = s_cnt;
    for (int i = tid; i < 512; i += 256) if (i >= (int)cnt) comp[i] = 0ULL;
    __syncthreads();

    // sort 512 desc: waves 0,1 wave-locally sort their 256-seg, then merge
    if (wv < 2)
        for (int k = 2; k <= 256; k <<= 1)
            wave_rounds256(comp, wv * 256, k, k >> 1, lane);
    __syncthreads();
    if (tid < 256) ce_desc(comp, tid, 256, 512);   // k=512, j=256 cross
    __syncthreads();
    if (wv < 2) wave_rounds256(comp, wv * 256, 512, 128, lane);
    __syncthreads();

    // decode top-200
    const float* xb = x + (size_t)b * NN * ROW;
    if (tid < OUT_K) {
        u64 kk = comp[tid];
        float* o = out + ((size_t)b * OUT_K + tid) * 6;
        if (kk == 0ULL) {
            o[0] = 0.f; o[1] = 0.f; o[2] = 0.f; o[3] = 0.f; o[4] = 0.f; o[5] = 0.f;
        } else {
            u32 flat = 0xFFFFFFFFu - (u32)(kk & 0xFFFFFFFFu);  // c*200 + slot
            int cls = flat / OUT_K;
            u32 n = cand_idx[(size_t)b * TOT + flat];
            float sc = __uint_as_float((u32)(kk >> 32));
            float4 bx = *(const float4*)(xb + (size_t)n * ROW);
            o[0] = (float)cls;
            o[1] = sc;
            o[2] = fminf(fmaxf(bx.x, 0.0f), 1.0f);
            o[3] = fminf(fmaxf(bx.y, 0.0f), 1.0f);
            o[4] = fminf(fmaxf(bx.z, 0.0f), 1.0f);
            o[5] = fminf(fmaxf(bx.w, 0.0f), 1.0f);
        }
    }
}

extern "C" void kernel_launch(void* const* d_in, const int* in_sizes, int n_in,
                              void* d_out, int out_size, void* d_ws, size_t ws_size,
                              hipStream_t stream) {
    const float* x = (const float*)d_in[0];
    float* out = (float*)d_out;
    // ws layout: cand_key 8*16000*8 = 1,024,000 B; cand_idx 8*16000*2 = 256,000 B
    u64* cand_key = (u64*)d_ws;
    u16* cand_idx = (u16*)((char*)d_ws + (size_t)NB * NC * OUT_K * sizeof(u64));
    nms_kernel<<<NB * NC, 256, 0, stream>>>(x, cand_key, cand_idx);
    topk_kernel<<<NB, 256, 0, stream>>>(x, cand_key, cand_idx, out);
}

// Round 5
// 206.907 us; speedup vs baseline: 8.0610x; 1.1649x over previous
//
#include <hip/hip_runtime.h>
#include <stdint.h>

typedef unsigned long long u64;
typedef unsigned int u32;
typedef unsigned short u16;

#define NB 8
#define NN 2048
#define NC 80
#define ROW 84
#define OUT_K 200
#define IOU_T 0.5f
#define SCORE_T 0.01f

// ---- compare-exchange, descending network, direction from global index ----
__device__ __forceinline__ void ce_desc(u64* a, int i, int j, int k) {
    u64 a0 = a[i], a1 = a[i + j];
    bool up = ((i & k) == 0);
    if (up ? (a0 < a1) : (a0 > a1)) { a[i] = a1; a[i + j] = a0; }
}

// wave-local rounds on a 512-elem segment (4 CE/lane/round), j<=256
__device__ __forceinline__ void wave_rounds512(u64* a, int base, int k, int jhi, int lane) {
    for (int j = jhi; j > 0; j >>= 1) {
        #pragma unroll
        for (int p = 0; p < 4; p++) {
            int r = lane + p * 64;
            int low = r & (j - 1);
            int high = (r & ~(j - 1)) << 1;
            ce_desc(a, base + (high | low), j, k);
        }
        __builtin_amdgcn_wave_barrier();   // order stages; DS is in-order per wave
    }
}

// wave-local rounds on a 256-elem segment (2 CE/lane/round), j<=128
__device__ __forceinline__ void wave_rounds256(u64* a, int base, int k, int jhi, int lane) {
    for (int j = jhi; j > 0; j >>= 1) {
        #pragma unroll
        for (int p = 0; p < 2; p++) {
            int r = lane + p * 64;
            int low = r & (j - 1);
            int high = (r & ~(j - 1)) << 1;
            ce_desc(a, base + (high | low), j, k);
        }
        __builtin_amdgcn_wave_barrier();
    }
}

// exact reference-order IoU > 0.5 test (identical to passing round-3/4 logic)
__device__ __forceinline__ bool iou_gt_half(float4 a, float aa, float4 b, float ab) {
    float ltx = fmaxf(a.x, b.x);
    float lty = fmaxf(a.y, b.y);
    float rbx = fminf(a.z, b.z);
    float rby = fminf(a.w, b.w);
    float wd = fmaxf(__fsub_rn(rbx, ltx), 0.0f);
    float hd = fmaxf(__fsub_rn(rby, lty), 0.0f);
    float inter = __fmul_rn(wd, hd);
    float uni = __fsub_rn(__fadd_rn(aa, ab), inter);
    float m = fmaxf(uni, 1e-8f);
    float d2 = __fmul_rn(2.0f, inter);     // exact scaling
    bool sup = d2 > m;                      // == (inter/m > 0.5) exactly
    if (sup && (__fsub_rn(d2, m) <= __fmul_rn(m, 1.2e-7f)))
        sup = __fdiv_rn(inter, m) > IOU_T;  // fdiv boundary guard, ~never taken
    return sup;
}

__device__ __forceinline__ float bcast(float v, int sl) {
    return __int_as_float(__builtin_amdgcn_readlane(__float_as_int(v), sl));
}

// ---- Kernel A: per (b,c): 4-wave hybrid sort, then single-wave chunked greedy ----
__global__ __launch_bounds__(256) void nms_kernel(
        const float* __restrict__ x, u64* __restrict__ cand_key,
        u16* __restrict__ cand_idx) {
    const int bc = blockIdx.x;
    const int b = bc / NC;
    const int c = bc % NC;
    const int tid = threadIdx.x;
    const int lane = tid & 63;
    const int wv = tid >> 6;
    const int base = wv * 512;

    __shared__ u64 key[NN];            // (score_bits<<32) | (0xFFFFFFFF - orig_idx)
    __shared__ float4 kept_box[OUT_K];
    __shared__ float kept_area[OUT_K];
    __shared__ u64 kept_key[OUT_K];
    __shared__ int s_kept;

    const float* xb = x + (size_t)b * NN * ROW;

    // build keys (score desc, index asc)
    #pragma unroll
    for (int w = 0; w < 8; w++) {
        int n = w * 256 + tid;
        float sc = xb[n * ROW + 4 + c];
        key[n] = ((u64)__float_as_uint(sc) << 32) | (u64)(0xFFFFFFFFu - (u32)n);
    }
    __syncthreads();

    // hybrid bitonic sort of 2048, descending.
    for (int k = 2; k <= 512; k <<= 1)
        wave_rounds512(key, base, k, k >> 1, lane);
    __syncthreads();
    #pragma unroll
    for (int p = 0; p < 4; p++) {                      // k=1024, j=512 cross
        int r = tid + p * 256;
        int low = r & 511, high = (r & ~511) << 1;
        ce_desc(key, high | low, 512, 1024);
    }
    __syncthreads();
    wave_rounds512(key, base, 1024, 256, lane);
    __syncthreads();
    #pragma unroll
    for (int p = 0; p < 4; p++) {                      // k=2048, j=1024 cross
        int r = tid + p * 256;
        int low = r & 1023, high = (r & ~1023) << 1;
        ce_desc(key, high | low, 1024, 2048);
    }
    __syncthreads();
    #pragma unroll
    for (int p = 0; p < 4; p++) {                      // k=2048, j=512 cross
        int r = tid + p * 256;
        int low = r & 511, high = (r & ~511) << 1;
        ce_desc(key, high | low, 512, 2048);
    }
    __syncthreads();
    wave_rounds512(key, base, 2048, 256, lane);
    __syncthreads();

    // ---- single-wave chunked greedy (wave 0), no barriers ----
    if (wv == 0) {
        int kept = 0;
        bool done = false;
        for (int ch = 0; ch < 32 && !done; ch++) {
            int n = ch * 64 + lane;
            u64 mykey = key[n];
            float sc = __uint_as_float((u32)(mykey >> 32));
            bool valid = sc > SCORE_T;
            u64 vball = __ballot(valid);
            if (vball == 0ULL) break;

            u32 orig = 0xFFFFFFFFu - (u32)(mykey & 0xFFFFFFFFu);
            float4 bx = *(const float4*)(xb + (size_t)orig * ROW);
            float ar = __fmul_rn(__fsub_rn(bx.z, bx.x), __fsub_rn(bx.w, bx.y));

            // data-parallel test vs kept list: unrolled x8, batched LDS reads
            bool alive_f = valid;
            int t = 0;
            for (; t + 8 <= kept; t += 8) {
                float4 kb0 = kept_box[t+0], kb1 = kept_box[t+1];
                float4 kb2 = kept_box[t+2], kb3 = kept_box[t+3];
                float4 kb4 = kept_box[t+4], kb5 = kept_box[t+5];
                float4 kb6 = kept_box[t+6], kb7 = kept_box[t+7];
                float ka0 = kept_area[t+0], ka1 = kept_area[t+1];
                float ka2 = kept_area[t+2], ka3 = kept_area[t+3];
                float ka4 = kept_area[t+4], ka5 = kept_area[t+5];
                float ka6 = kept_area[t+6], ka7 = kept_area[t+7];
                bool s0 = iou_gt_half(bx, ar, kb0, ka0);
                bool s1 = iou_gt_half(bx, ar, kb1, ka1);
                bool s2 = iou_gt_half(bx, ar, kb2, ka2);
                bool s3 = iou_gt_half(bx, ar, kb3, ka3);
                bool s4 = iou_gt_half(bx, ar, kb4, ka4);
                bool s5 = iou_gt_half(bx, ar, kb5, ka5);
                bool s6 = iou_gt_half(bx, ar, kb6, ka6);
                bool s7 = iou_gt_half(bx, ar, kb7, ka7);
                bool any = (s0 | s1 | s2 | s3) | (s4 | s5 | s6 | s7);
                alive_f = alive_f && !any;
            }
            for (; t < kept; t++) {
                if (iou_gt_half(bx, ar, kept_box[t], kept_area[t])) alive_f = false;
            }
            u64 alive = __ballot(alive_f);

            // wave-serial scan: one step per KEPT box; scalar broadcasts
            while (alive) {
                int bsel = (int)__builtin_ctzll(alive);
                if (lane == bsel) {
                    kept_key[kept] = mykey;
                    kept_box[kept] = bx;
                    kept_area[kept] = ar;
                }
                kept++;
                if (kept >= OUT_K) { done = true; break; }
                alive &= alive - 1;               // clear bsel
                if (!alive) break;
                float4 pb = make_float4(bcast(bx.x, bsel), bcast(bx.y, bsel),
                                        bcast(bx.z, bsel), bcast(bx.w, bsel));
                float pa = bcast(ar, bsel);
                bool sup = iou_gt_half(bx, ar, pb, pa);
                alive &= ~__ballot(sup);
            }
            __builtin_amdgcn_wave_barrier();      // kept_* writes ordered vs next chunk reads
            if (__popcll(vball) < 64) break;      // sorted: nothing valid beyond
        }
        if (lane == 0) s_kept = kept;
    }
    __syncthreads();

    // emit 200 candidate slots per (b,c); empty -> key 0 (invalid)
    const int base_o = (b * NC + c) * OUT_K;
    if (tid < OUT_K) {
        u64 ok = 0ULL; u16 oi = 0;
        if (tid < s_kept) {
            u64 kk = kept_key[tid];
            // tie-break index (c*200+slot) preserves reference (c*N+pos) order
            ok = (kk & 0xFFFFFFFF00000000ULL) |
                 (u64)(0xFFFFFFFFu - (u32)(c * OUT_K + tid));
            oi = (u16)(0xFFFFFFFFu - (u32)(kk & 0xFFFFFFFFu));
        }
        cand_key[base_o + tid] = ok;
        cand_idx[base_o + tid] = oi;
    }
}

// ---- Kernel B: 8 blocks x 1024 threads; histogram-select + sort + decode ----
__device__ __forceinline__ u32 key_bin(u64 kk) {
    u32 sb = (u32)(kk >> 32);
    int bi = (int)(sb >> 13) - 122880;   // 0x3C000000>>13; scores<2^-7 clamp to 0
    return (u32)min(max(bi, 0), 8191);
}

__global__ __launch_bounds__(1024) void topk_kernel(
        const float* __restrict__ x, const u64* __restrict__ cand_key,
        const u16* __restrict__ cand_idx, float* __restrict__ out) {
    const int b = blockIdx.x;
    const int tid = threadIdx.x;
    const int lane = tid & 63;
    const int wv = tid >> 6;              // 16 waves
    const int TOT = NC * OUT_K;           // 16000

    __shared__ u32 hist[8192];            // 32 KB
    __shared__ u32 wsum[16];
    __shared__ u64 comp[512];
    __shared__ u32 s_cnt, s_thr;

    const u64* ck = cand_key + (size_t)b * TOT;

    for (int i = tid; i < 8192; i += 1024) hist[i] = 0;
    if (tid == 0) { s_cnt = 0; s_thr = 0; }
    __syncthreads();

    // histogram of nonzero keys (coalesced: 16 keys/thread)
    #pragma unroll
    for (int q = 0; q < 16; q++) {
        int i = tid + q * 1024;
        if (i < TOT) {
            u64 kk = ck[i];
            if (kk) atomicAdd(&hist[key_bin(kk)], 1);
        }
    }
    __syncthreads();

    // per-thread sum over contiguous 8-bin range, then parallel suffix scan
    u32 loc = 0;
    #pragma unroll
    for (int q = 0; q < 8; q++) loc += hist[tid * 8 + q];
    u32 incl = loc;                       // wave-level inclusive suffix sum
    #pragma unroll
    for (int off = 1; off < 64; off <<= 1) {
        u32 v = __shfl_down(incl, off, 64);
        if (lane + off < 64) incl += v;
    }
    if (lane == 0) wsum[wv] = incl;       // wave total (suffix at lane 0)
    __syncthreads();
    u32 wbase = 0;
    #pragma unroll
    for (int w = 0; w < 16; w++) wbase += (w > wv) ? wsum[w] : 0;
    u32 S = wbase + (incl - loc);         // exclusive suffix above this range

    // threshold bin: unique (tid,q) where cumulative crosses OUT_K
    {
        u32 cum = S;
        #pragma unroll
        for (int q = 7; q >= 0; q--) {
            u32 cnt = hist[tid * 8 + q];
            if (cum < OUT_K && cum + cnt >= OUT_K) s_thr = (u32)(tid * 8 + q);
            cum += cnt;
        }
    }
    __syncthreads();
    const u32 thr = s_thr;

    // compact qualifying keys (bin >= thr is an exact superset of top-200)
    #pragma unroll
    for (int q = 0; q < 16; q++) {
        int i = tid + q * 1024;
        if (i < TOT) {
            u64 kk = ck[i];
            if (kk && key_bin(kk) >= thr) {
                u32 p = atomicAdd(&s_cnt, 1);
                if (p < 512) comp[p] = kk;
            }
        }
    }
    __syncthreads();
    const u32 cnt = s_cnt;
    for (int i = tid; i < 512; i += 1024) if (i >= (int)cnt) comp[i] = 0ULL;
    __syncthreads();

    // sort 512 desc: waves 0,1 wave-local on 256-segs, then cross-merge
    if (wv < 2)
        for (int k = 2; k <= 256; k <<= 1)
            wave_rounds256(comp, wv * 256, k, k >> 1, lane);
    __syncthreads();
    if (tid < 256) ce_desc(comp, tid, 256, 512);   // k=512, j=256 cross
    __syncthreads();
    if (wv < 2) wave_rounds256(comp, wv * 256, 512, 128, lane);
    __syncthreads();

    // decode top-200
    const float* xb = x + (size_t)b * NN * ROW;
    if (tid < OUT_K) {
        u64 kk = comp[tid];
        float* o = out + ((size_t)b * OUT_K + tid) * 6;
        if (kk == 0ULL) {
            o[0] = 0.f; o[1] = 0.f; o[2] = 0.f; o[3] = 0.f; o[4] = 0.f; o[5] = 0.f;
        } else {
            u32 flat = 0xFFFFFFFFu - (u32)(kk & 0xFFFFFFFFu);  // c*200 + slot
            int cls = flat / OUT_K;
            u32 n = cand_idx[(size_t)b * TOT + flat];
            float sc = __uint_as_float((u32)(kk >> 32));
            float4 bx = *(const float4*)(xb + (size_t)n * ROW);
            o[0] = (float)cls;
            o[1] = sc;
            o[2] = fminf(fmaxf(bx.x, 0.0f), 1.0f);
            o[3] = fminf(fmaxf(bx.y, 0.0f), 1.0f);
            o[4] = fminf(fmaxf(bx.z, 0.0f), 1.0f);
            o[5] = fminf(fmaxf(bx.w, 0.0f), 1.0f);
        }
    }
}

extern "C" void kernel_launch(void* const* d_in, const int* in_sizes, int n_in,
                              void* d_out, int out_size, void* d_ws, size_t ws_size,
                              hipStream_t stream) {
    const float* x = (const float*)d_in[0];
    float* out = (float*)d_out;
    // ws layout: cand_key 8*16000*8 = 1,024,000 B; cand_idx 8*16000*2 = 256,000 B
    u64* cand_key = (u64*)d_ws;
    u16* cand_idx = (u16*)((char*)d_ws + (size_t)NB * NC * OUT_K * sizeof(u64));
    nms_kernel<<<NB * NC, 256, 0, stream>>>(x, cand_key, cand_idx);
    topk_kernel<<<NB, 1024, 0, stream>>>(x, cand_key, cand_idx, out);
}

// Round 6
// 190.404 us; speedup vs baseline: 8.7597x; 1.0867x over previous
//
#include <hip/hip_runtime.h>
#include <stdint.h>

typedef unsigned long long u64;
typedef unsigned int u32;
typedef unsigned short u16;

#define NB 8
#define NN 2048
#define NC 80
#define ROW 84
#define OUT_K 200
#define IOU_T 0.5f
#define SCORE_T 0.01f

// ---- compare-exchange, descending network, direction from global index ----
__device__ __forceinline__ void ce_desc(u64* a, int i, int j, int k) {
    u64 a0 = a[i], a1 = a[i + j];
    bool up = ((i & k) == 0);
    if (up ? (a0 < a1) : (a0 > a1)) { a[i] = a1; a[i + j] = a0; }
}

// wave-local rounds on a 512-elem segment (4 CE/lane/round), j<=256
__device__ __forceinline__ void wave_rounds512(u64* a, int base, int k, int jhi, int lane) {
    for (int j = jhi; j > 0; j >>= 1) {
        #pragma unroll
        for (int p = 0; p < 4; p++) {
            int r = lane + p * 64;
            int low = r & (j - 1);
            int high = (r & ~(j - 1)) << 1;
            ce_desc(a, base + (high | low), j, k);
        }
        __builtin_amdgcn_wave_barrier();   // order stages; DS is in-order per wave
    }
}

// wave-local rounds on a 256-elem segment (2 CE/lane/round), j<=128
// pass k = 0x40000000 for an all-descending (plain bitonic merge) network
__device__ __forceinline__ void wave_rounds256(u64* a, int base, int k, int jhi, int lane) {
    for (int j = jhi; j > 0; j >>= 1) {
        #pragma unroll
        for (int p = 0; p < 2; p++) {
            int r = lane + p * 64;
            int low = r & (j - 1);
            int high = (r & ~(j - 1)) << 1;
            ce_desc(a, base + (high | low), j, k);
        }
        __builtin_amdgcn_wave_barrier();
    }
}

// max-combine two desc-sorted 256-runs (at base, base+off) into bitonic
// 256 at base, then merge descending -> top-256 of the pair, sorted desc
__device__ __forceinline__ void pair_merge256(u64* a, int base, int off, int lane) {
    #pragma unroll
    for (int p0 = 0; p0 < 4; p0++) {
        int p = lane + p0 * 64;
        u64 xv = a[base + p];
        u64 yv = a[base + off + 255 - p];
        a[base + p] = xv > yv ? xv : yv;
    }
    __builtin_amdgcn_wave_barrier();
    wave_rounds256(a, base, 0x40000000, 128, lane);
}

// exact reference-order IoU > 0.5 test (identical to passing round-3/4/5 logic)
__device__ __forceinline__ bool iou_gt_half(float4 a, float aa, float4 b, float ab) {
    float ltx = fmaxf(a.x, b.x);
    float lty = fmaxf(a.y, b.y);
    float rbx = fminf(a.z, b.z);
    float rby = fminf(a.w, b.w);
    float wd = fmaxf(__fsub_rn(rbx, ltx), 0.0f);
    float hd = fmaxf(__fsub_rn(rby, lty), 0.0f);
    float inter = __fmul_rn(wd, hd);
    float uni = __fsub_rn(__fadd_rn(aa, ab), inter);
    float m = fmaxf(uni, 1e-8f);
    float d2 = __fmul_rn(2.0f, inter);     // exact scaling
    bool sup = d2 > m;                      // == (inter/m > 0.5) exactly
    if (sup && (__fsub_rn(d2, m) <= __fmul_rn(m, 1.2e-7f)))
        sup = __fdiv_rn(inter, m) > IOU_T;  // fdiv boundary guard, ~never taken
    return sup;
}

__device__ __forceinline__ float bcast(float v, int sl) {
    return __int_as_float(__builtin_amdgcn_readlane(__float_as_int(v), sl));
}

// ---- Kernel A: per (b,c): 4-wave hybrid sort; 4-wave kept-test + 1-wave scan ----
__global__ __launch_bounds__(256) void nms_kernel(
        const float* __restrict__ x, u64* __restrict__ cand_key,
        u16* __restrict__ cand_idx) {
    const int bc = blockIdx.x;
    const int b = bc / NC;
    const int c = bc % NC;
    const int tid = threadIdx.x;
    const int lane = tid & 63;
    const int wv = tid >> 6;
    const int base = wv * 512;

    __shared__ u64 key[NN];            // (score_bits<<32) | (0xFFFFFFFF - orig_idx)
    __shared__ float4 kept_box[OUT_K];
    __shared__ float kept_area[OUT_K];
    __shared__ u64 kept_key[OUT_K];
    __shared__ u64 s_sup[4];
    __shared__ int s_kept, s_done;

    const float* xb = x + (size_t)b * NN * ROW;

    // build keys (score desc, index asc)
    #pragma unroll
    for (int w = 0; w < 8; w++) {
        int n = w * 256 + tid;
        float sc = xb[n * ROW + 4 + c];
        key[n] = ((u64)__float_as_uint(sc) << 32) | (u64)(0xFFFFFFFFu - (u32)n);
    }
    __syncthreads();

    // hybrid bitonic sort of 2048, descending.
    for (int k = 2; k <= 512; k <<= 1)
        wave_rounds512(key, base, k, k >> 1, lane);
    __syncthreads();
    #pragma unroll
    for (int p = 0; p < 4; p++) {                      // k=1024, j=512 cross
        int r = tid + p * 256;
        int low = r & 511, high = (r & ~511) << 1;
        ce_desc(key, high | low, 512, 1024);
    }
    __syncthreads();
    wave_rounds512(key, base, 1024, 256, lane);
    __syncthreads();
    #pragma unroll
    for (int p = 0; p < 4; p++) {                      // k=2048, j=1024 cross
        int r = tid + p * 256;
        int low = r & 1023, high = (r & ~1023) << 1;
        ce_desc(key, high | low, 1024, 2048);
    }
    __syncthreads();
    #pragma unroll
    for (int p = 0; p < 4; p++) {                      // k=2048, j=512 cross
        int r = tid + p * 256;
        int low = r & 511, high = (r & ~511) << 1;
        ce_desc(key, high | low, 512, 2048);
    }
    __syncthreads();
    if (tid == 0) { s_kept = 0; s_done = 0; }
    wave_rounds512(key, base, 2048, 256, lane);
    __syncthreads();

    // ---- chunked greedy: all 4 waves split the kept-list test; wave 0 scans ----
    int keptc = 0;                         // kept count (consistent across waves)
    for (int ch = 0; ch < 32; ch++) {
        int n = ch * 64 + lane;
        u64 mykey = key[n];
        float sc = __uint_as_float((u32)(mykey >> 32));
        bool valid = sc > SCORE_T;
        u64 vball = __ballot(valid);       // identical on all 4 waves
        if (vball == 0ULL) break;

        u32 orig = 0xFFFFFFFFu - (u32)(mykey & 0xFFFFFFFFu);
        float4 bx = *(const float4*)(xb + (size_t)orig * ROW);
        float ar = __fmul_rn(__fsub_rn(bx.z, bx.x), __fsub_rn(bx.w, bx.y));

        // wave wv tests candidates vs kept[t], t ≡ wv (mod 4); same-address
        // LDS reads broadcast, x4 batched for latency
        bool supA = false;
        int t = wv;
        for (; t + 12 < keptc; t += 16) {
            float4 kb0 = kept_box[t],     kb1 = kept_box[t + 4];
            float4 kb2 = kept_box[t + 8], kb3 = kept_box[t + 12];
            float ka0 = kept_area[t],     ka1 = kept_area[t + 4];
            float ka2 = kept_area[t + 8], ka3 = kept_area[t + 12];
            bool s0 = iou_gt_half(bx, ar, kb0, ka0);
            bool s1 = iou_gt_half(bx, ar, kb1, ka1);
            bool s2 = iou_gt_half(bx, ar, kb2, ka2);
            bool s3 = iou_gt_half(bx, ar, kb3, ka3);
            supA = supA | ((s0 | s1) | (s2 | s3));
        }
        for (; t < keptc; t += 4)
            supA = supA | iou_gt_half(bx, ar, kept_box[t], kept_area[t]);
        u64 supm = __ballot(supA);
        if (lane == 0) s_sup[wv] = supm;
        __syncthreads();                   // B1: sup masks visible

        if (wv == 0) {
            u64 alive = vball & ~s_sup[0] & ~s_sup[1] & ~s_sup[2] & ~s_sup[3];
            int kept = keptc;
            // wave-serial scan: one step per KEPT box; scalar broadcasts
            while (alive) {
                int bsel = (int)__builtin_ctzll(alive);
                if (lane == bsel) {
                    kept_key[kept] = mykey;
                    kept_box[kept] = bx;
                    kept_area[kept] = ar;
                }
                kept++;
                if (kept >= OUT_K) { s_done = 1; break; }
                alive &= alive - 1;        // clear bsel
                if (!alive) break;
                float4 pb = make_float4(bcast(bx.x, bsel), bcast(bx.y, bsel),
                                        bcast(bx.z, bsel), bcast(bx.w, bsel));
                float pa = bcast(ar, bsel);
                bool sup = iou_gt_half(bx, ar, pb, pa);
                alive &= ~__ballot(sup);
            }
            if (lane == 0) s_kept = kept;
        }
        __syncthreads();                   // B2: kept list + count + done visible
        keptc = s_kept;
        if (s_done) break;
        if (__popcll(vball) < 64) break;   // sorted: nothing valid beyond
    }
    __syncthreads();

    // emit 200 candidate slots per (b,c); empty -> key 0 (invalid)
    const int base_o = (b * NC + c) * OUT_K;
    if (tid < OUT_K) {
        u64 ok = 0ULL; u16 oi = 0;
        if (tid < s_kept) {
            u64 kk = kept_key[tid];
            // tie-break index (c*200+slot) preserves reference (c*N+pos) order
            ok = (kk & 0xFFFFFFFF00000000ULL) |
                 (u64)(0xFFFFFFFFu - (u32)(c * OUT_K + tid));
            oi = (u16)(0xFFFFFFFFu - (u32)(kk & 0xFFFFFFFFu));
        }
        cand_key[base_o + tid] = ok;
        cand_idx[base_o + tid] = oi;
    }
}

// ---- Kernel B1: 80 blocks; tournament-merge 8 desc runs of 200 -> top-256 ----
__global__ __launch_bounds__(256) void topk_stage1(
        const u64* __restrict__ cand_key, u64* __restrict__ ws2) {
    const int b = blockIdx.x / 10, ch = blockIdx.x % 10;
    const int tid = threadIdx.x;
    const int lane = tid & 63;
    const int wv = tid >> 6;
    __shared__ u64 A[2048];
    const u64* src = cand_key + (size_t)b * (NC * OUT_K) + (size_t)ch * 8 * OUT_K;
    for (int i = tid; i < 2048; i += 256) {
        int run = i >> 8, pos = i & 255;
        A[i] = (pos < OUT_K) ? src[run * OUT_K + pos] : 0ULL;
    }
    __syncthreads();
    // L1: each wave merges its own pair (disjoint 512 regions)
    pair_merge256(A, wv * 512, 256, lane);
    __syncthreads();
    // L2: waves 0,1 merge runs at stride 512
    if (wv < 2) pair_merge256(A, wv * 1024, 512, lane);
    __syncthreads();
    // L3: wave 0 merges runs at stride 1024
    if (wv == 0) pair_merge256(A, 0, 1024, lane);
    __syncthreads();
    ws2[(size_t)b * 2560 + ch * 256 + tid] = A[tid];
}

// ---- Kernel B2: 8 blocks; merge 10 runs of 256 (pad 16) -> decode top-200 ----
__global__ __launch_bounds__(256) void topk_stage2(
        const float* __restrict__ x, const u64* __restrict__ ws2,
        const u16* __restrict__ cand_idx, float* __restrict__ out) {
    const int b = blockIdx.x;
    const int tid = threadIdx.x;
    const int lane = tid & 63;
    const int wv = tid >> 6;
    __shared__ u64 A[4096];
    for (int i = tid; i < 4096; i += 256)
        A[i] = (i < 2560) ? ws2[(size_t)b * 2560 + i] : 0ULL;
    __syncthreads();
    // L1: 8 pairs at stride 256; wave wv does pairs wv and wv+4
    pair_merge256(A, wv * 512, 256, lane);
    pair_merge256(A, (wv + 4) * 512, 256, lane);
    __syncthreads();
    // L2: 4 pairs at stride 512
    pair_merge256(A, wv * 1024, 512, lane);
    __syncthreads();
    // L3: 2 pairs at stride 1024
    if (wv < 2) pair_merge256(A, wv * 2048, 1024, lane);
    __syncthreads();
    // L4: final pair at stride 2048
    if (wv == 0) pair_merge256(A, 0, 2048, lane);
    __syncthreads();

    // decode top-200
    const float* xb = x + (size_t)b * NN * ROW;
    if (tid < OUT_K) {
        u64 kk = A[tid];
        float* o = out + ((size_t)b * OUT_K + tid) * 6;
        if (kk == 0ULL) {
            o[0] = 0.f; o[1] = 0.f; o[2] = 0.f; o[3] = 0.f; o[4] = 0.f; o[5] = 0.f;
        } else {
            u32 flat = 0xFFFFFFFFu - (u32)(kk & 0xFFFFFFFFu);  // c*200 + slot
            int cls = flat / OUT_K;
            u32 n = cand_idx[(size_t)b * (NC * OUT_K) + flat];
            float sc = __uint_as_float((u32)(kk >> 32));
            float4 bx = *(const float4*)(xb + (size_t)n * ROW);
            o[0] = (float)cls;
            o[1] = sc;
            o[2] = fminf(fmaxf(bx.x, 0.0f), 1.0f);
            o[3] = fminf(fmaxf(bx.y, 0.0f), 1.0f);
            o[4] = fminf(fmaxf(bx.z, 0.0f), 1.0f);
            o[5] = fminf(fmaxf(bx.w, 0.0f), 1.0f);
        }
    }
}

extern "C" void kernel_launch(void* const* d_in, const int* in_sizes, int n_in,
                              void* d_out, int out_size, void* d_ws, size_t ws_size,
                              hipStream_t stream) {
    const float* x = (const float*)d_in[0];
    float* out = (float*)d_out;
    // ws layout: cand_key 8*16000*8 = 1,024,000 B
    //            cand_idx 8*16000*2 =   256,000 B
    //            ws2      8*2560*8  =   163,840 B   (total ~1.44 MB)
    u64* cand_key = (u64*)d_ws;
    u16* cand_idx = (u16*)((char*)d_ws + (size_t)NB * NC * OUT_K * sizeof(u64));
    u64* ws2 = (u64*)((char*)d_ws + (size_t)NB * NC * OUT_K * (sizeof(u64) + sizeof(u16)));
    nms_kernel<<<NB * NC, 256, 0, stream>>>(x, cand_key, cand_idx);
    topk_stage1<<<NB * 10, 256, 0, stream>>>(cand_key, ws2);
    topk_stage2<<<NB, 256, 0, stream>>>(x, ws2, cand_idx, out);
}